// Round 1
// 1480.917 us; speedup vs baseline: 1.1644x; 1.1644x over previous
//
#include <hip/hip_runtime.h>
#include <cstdint>
#include <cstddef>

#define B_DIM 128
#define T_LEN 2048
#define C_DIM 128
#define NSTEP (T_LEN - 1)   // 2047 transition steps
#define NS4   512           // ceil(2047/4) dword-rows per batch (old bp4 path)

// Skew: F(x) = x + 8*(x>>5). 32-float chunk c sits at 40c; the 4 chunks'
// ds_read_b128 streams hit disjoint bank quartets (perfect 32-bank perm).
#define FSKEW(x) ((x) + 8 * ((x) >> 5))

// Barrier WITHOUT vmcnt drain: __syncthreads() emits
// s_waitcnt vmcnt(0) lgkmcnt(0) before s_barrier, draining the in-flight
// pot prefetch + global stores every step. Cross-wave LDS visibility only
// needs lgkmcnt(0); global ops stay in flight across the barrier.
#define LDS_BARRIER() asm volatile("s_waitcnt lgkmcnt(0)\n\ts_barrier" ::: "memory")

// 32 trans values as NAMED SCALARS (resident VGPRs).
#define TR_LIST(X) \
    X(0)  X(1)  X(2)  X(3)  X(4)  X(5)  X(6)  X(7)  \
    X(8)  X(9)  X(10) X(11) X(12) X(13) X(14) X(15) \
    X(16) X(17) X(18) X(19) X(20) X(21) X(22) X(23) \
    X(24) X(25) X(26) X(27) X(28) X(29) X(30) X(31)

template <int CTRL>
__device__ __forceinline__ float dppf(float x)
{
    return __int_as_float(__builtin_amdgcn_update_dpp(
        0, __float_as_int(x), CTRL, 0xF, 0xF, true));
}

// ===========================================================================
// NEW PATH: value-only forward (stores exact f32 alpha rows), argmax is
// recomputed on the backtrack path only. Removes the 93-instr index
// tournament from the 2047-step serial critical chain.
// ===========================================================================

// Forward, value-only. One block per batch, 512 threads = 8 waves.
// Wave w owns j in [16w,16w+16); lane l: j = 16w + (l>>2), d = l&3,
// i in [32d,32d+32). Per step: 32 adds + max3-tree (value only) + 2 DPP
// quad_perm max rounds; d==0 lanes write alpha to LDS (next step) and to
// global alphaG row T_ (consumed by backtrack). ONE lgkm-only barrier/step.
__global__ __launch_bounds__(512)
__attribute__((amdgpu_waves_per_eu(2, 2)))
void viterbi_fwd_a(
    const float* __restrict__ pot,
    const float* __restrict__ trans,
    float* __restrict__ alphaG,        // [B][2047][C]: row r = alpha_r, r=0..2046
    int* __restrict__ lastTag)
{
    const int b   = blockIdx.x;
    const int tid = threadIdx.x;
    const int w   = tid >> 6;
    const int l   = tid & 63;
    const int d   = l & 3;             // i-chunk: [32d, 32d+32)
    const int j   = 16 * w + (l >> 2);
    const int fj  = FSKEW(j);
    const int ib  = 32 * d;
    (void)ib;

    __shared__ __align__(16) float alphabuf[2][160];

#define DECL_TR(K) float tr_##K = trans[(ib + (K)) * C_DIM + j];
    TR_LIST(DECL_TR)
#undef DECL_TR

    const float* potb = pot + (size_t)b * T_LEN * C_DIM;
    float* aG = alphaG + (size_t)b * NSTEP * C_DIM;

    // alpha0 = pot[:,0]: into buf[1] (step t=1 reads buf[t&1]=buf[1]) and row 0
    if (tid < C_DIM) {
        const float a0 = potb[tid];
        alphabuf[1][FSKEW(tid)] = a0;
        aG[tid] = a0;
    }

    // pot prefetch queue, depth 4 (d==0 lanes only consume it)
    float pq0 = 0.f, pq1 = 0.f, pq2 = 0.f, pq3 = 0.f;
    if (d == 0) {
        pq0 = potb[1 * C_DIM + j];
        pq1 = potb[2 * C_DIM + j];
        pq2 = potb[3 * C_DIM + j];
        pq3 = potb[4 * C_DIM + j];
    }
    __syncthreads();   // init barrier: full drain once, fine

#define ADD_TR(K) s_[K] = a_[K] + tr_##K;

#define STEP_A(T_, PQ_)                                                       \
    {                                                                         \
        const float* ac_ = &alphabuf[(T_) & 1][40 * d];                       \
        float a_[32];                                                         \
        _Pragma("unroll")                                                     \
        for (int e_ = 0; e_ < 8; ++e_)                                        \
            *(float4*)&a_[4 * e_] = *(const float4*)&ac_[4 * e_];             \
        float s_[32];                                                         \
        TR_LIST(ADD_TR)                                                       \
        /* value-only max tree (fuses to v_max3 chains) */                    \
        float u_[11];                                                         \
        _Pragma("unroll")                                                     \
        for (int p_ = 0; p_ < 10; ++p_)                                       \
            u_[p_] = fmaxf(fmaxf(s_[3 * p_], s_[3 * p_ + 1]), s_[3 * p_ + 2]);\
        u_[10] = fmaxf(s_[30], s_[31]);                                       \
        const float w0_ = fmaxf(fmaxf(u_[0], u_[1]), u_[2]);                  \
        const float w1_ = fmaxf(fmaxf(u_[3], u_[4]), u_[5]);                  \
        const float w2_ = fmaxf(fmaxf(u_[6], u_[7]), u_[8]);                  \
        const float w3_ = fmaxf(u_[9], u_[10]);                               \
        float v_ = fmaxf(fmaxf(w0_, w1_), fmaxf(w2_, w3_));                   \
        /* DPP quad_perm value-max merge across d (xor1, xor2) */             \
        v_ = fmaxf(v_, dppf<0xB1>(v_));                                       \
        v_ = fmaxf(v_, dppf<0x4E>(v_));                                       \
        if (d == 0) {                                                         \
            const float av_ = v_ + (PQ_);                                     \
            alphabuf[((T_) + 1) & 1][fj] = av_;                               \
            if ((T_) < T_LEN - 1)                                             \
                aG[(size_t)(T_) * C_DIM + j] = av_;                           \
            if ((T_) + 4 < T_LEN) PQ_ = potb[((T_) + 4) * C_DIM + j];         \
        }                                                                     \
        LDS_BARRIER();                                                        \
    }

    // main loop: t = 1 .. 2044 (groups of 4 for the pot-queue rotation)
    for (int t = 1; t < 2045; t += 4) {
        STEP_A(t + 0, pq0)
        STEP_A(t + 1, pq1)
        STEP_A(t + 2, pq2)
        STEP_A(t + 3, pq3)
    }
    // tail: t = 2045, 2046, 2047 (2047 skips the global store)
    STEP_A(2045, pq0)
    STEP_A(2046, pq1)
    STEP_A(2047, pq2)
#undef STEP_A
#undef ADD_TR

    // last_tag = first-index argmax of final alpha (in buf[0]), wave 0
    if (tid < 64) {
        const float* af = alphabuf[0];
        const float v0 = af[FSKEW(tid)];
        const float v1 = af[FSKEW(tid + 64)];
        float v = v0; int x = tid;
        if (v1 > v0) { v = v1; x = tid + 64; }
#pragma unroll
        for (int mk = 1; mk < 64; mk <<= 1) {
            const float pv = __shfl_xor(v, mk);
            const int   px = __shfl_xor(x, mk);
            if (pv > v || (pv == v && px < x)) { v = pv; x = px; }
        }
        if (tid == 0) lastTag[b] = x;
    }
}

// Backtrack with argmax recomputation. One wave per batch. T staged in LDS
// XOR-swizzled (Tl[i][j ^ (i&31)]) so the column gather T[:,cur] is
// bank-conflict-free (cur^(l&31) covers all 32 banks, 2 lanes/bank = free).
// Exact first-index argmax: value-max butterfly (all-VALU DPP xor1/2/7/15 +
// ds_swizzle xor16 + shfl xor32), then two ballots + ffs (i<64 checked
// before i>=64, lowest lane bit = lowest i). alpha rows prefetched 6 deep
// (addresses independent of cur).
__global__ __launch_bounds__(64, 1) void viterbi_bwd_a(
    const float* __restrict__ alphaG,
    const float* __restrict__ trans,
    const int* __restrict__ lastTag,
    float* __restrict__ out)
{
    const int b = blockIdx.x;
    const int l = threadIdx.x;
    float* outb = out + (size_t)b * T_LEN;

    __shared__ float Tl[C_DIM][C_DIM];   // 64 KiB, swizzled
    for (int k = l; k < C_DIM * C_DIM; k += 64) {
        const int i = k >> 7;
        const int jj = k & 127;
        Tl[i][jj ^ (i & 31)] = trans[k];  // stage writes: all 32 banks, 2/bank
    }

    const float* ab = alphaG + (size_t)b * NSTEP * C_DIM;

    float qa0 = 0.f, qb0 = 0.f, qa1 = 0.f, qb1 = 0.f, qa2 = 0.f, qb2 = 0.f,
          qa3 = 0.f, qb3 = 0.f, qa4 = 0.f, qb4 = 0.f, qa5 = 0.f, qb5 = 0.f;
    auto ld = [&](int r, float& A, float& Bv) {
        if (r >= 0) {
            const float* p = ab + (size_t)r * C_DIM;
            A  = p[l];
            Bv = p[l + 64];
        }
    };
    ld(2046, qa0, qb0);
    ld(2045, qa1, qb1);
    ld(2044, qa2, qb2);
    ld(2043, qa3, qb3);
    ld(2042, qa4, qb4);
    ld(2041, qa5, qb5);

    int cur = lastTag[b];
    if (l == 0) outb[T_LEN - 1] = (float)cur;
    __syncthreads();   // Tl visibility

    for (int t = T_LEN - 1; t >= 1; --t) {
        const float a0 = qa0, a1 = qb0;          // alpha_{t-1}[l], [l+64]
        const int sw = cur ^ (l & 31);
        const float c0 = Tl[l][sw];              // T[l][cur]
        const float c1 = Tl[l + 64][sw];         // T[l+64][cur]
        const float s0 = a0 + c0;
        const float s1 = a1 + c1;
        float v = fmaxf(s0, s1);
        // 64-lane value-max butterfly: masks {1,2,7,15,16,32} span all 6 bits
        v = fmaxf(v, dppf<0xB1>(v));             // quad_perm xor1
        v = fmaxf(v, dppf<0x4E>(v));             // quad_perm xor2
        v = fmaxf(v, dppf<0x141>(v));            // row_half_mirror = xor7
        v = fmaxf(v, dppf<0x140>(v));            // row_mirror = xor15
        v = fmaxf(v, __int_as_float(__builtin_amdgcn_ds_swizzle(
                         __float_as_int(v), 0x401F)));   // xor16
        v = fmaxf(v, __shfl_xor(v, 32));                 // xor32
        // exact first-index argmax: lowest i with s_i == max
        const unsigned long long m0 = __ballot(s0 == v);
        const unsigned long long m1 = __ballot(s1 == v);
        cur = m0 ? (__ffsll(m0) - 1) : (64 + __ffsll(m1) - 1);
        if (l == 0) outb[t - 1] = (float)cur;
        qa0 = qa1; qb0 = qb1; qa1 = qa2; qb1 = qb2;
        qa2 = qa3; qb2 = qb3; qa3 = qa4; qb3 = qb4;
        qa4 = qa5; qb4 = qb5;
        ld(t - 7, qa5, qb5);
    }
}

// ===========================================================================
// FALLBACK PATH (verbatim previous best, 1724 µs): used when ws_size cannot
// hold the 134 MB alpha store. bp4-based forward + byte-chase backtrack.
// ===========================================================================

__global__ __launch_bounds__(512)
__attribute__((amdgpu_waves_per_eu(2, 2)))
void viterbi_fwd(
    const float* __restrict__ pot,
    const float* __restrict__ trans,
    unsigned* __restrict__ bp4,        // [NS4][B][C] dwords, 4 steps packed/dword
    int* __restrict__ lastTag)
{
    const int b   = blockIdx.x;
    const int tid = threadIdx.x;
    const int w   = tid >> 6;
    const int l   = tid & 63;
    const int d   = l & 3;             // i-chunk: [32d, 32d+32)
    const int j   = 16 * w + (l >> 2);
    const int fj  = FSKEW(j);
    const int ib  = 32 * d;

    __shared__ __align__(16) float alphabuf[2][160];

#define DECL_TR(K) float tr_##K = trans[(ib + (K)) * C_DIM + j];
    TR_LIST(DECL_TR)
#undef DECL_TR

    const float* potb = pot + (size_t)b * T_LEN * C_DIM;

    if (tid < C_DIM) alphabuf[1][FSKEW(tid)] = potb[tid];

    float pq0 = 0.f, pq1 = 0.f, pq2 = 0.f, pq3 = 0.f;
    if (d == 0) {
        pq0 = potb[1 * C_DIM + j];
        pq1 = potb[2 * C_DIM + j];
        pq2 = potb[3 * C_DIM + j];
        pq3 = potb[4 * C_DIM + j];
    }
    unsigned pack = 0;
    __syncthreads();

#define ADD_TR(K) s_[K] = a_[K] + tr_##K;

#define STEP(T_, C_, PQ_)                                                     \
    {                                                                         \
        const float* ac_ = &alphabuf[(T_) & 1][40 * d];                       \
        float a_[32];                                                         \
        _Pragma("unroll")                                                     \
        for (int e_ = 0; e_ < 8; ++e_)                                        \
            *(float4*)&a_[4 * e_] = *(const float4*)&ac_[4 * e_];             \
        float s_[32];                                                         \
        TR_LIST(ADD_TR)                                                       \
        float v16_[16]; int x16_[16];                                         \
        _Pragma("unroll")                                                     \
        for (int p_ = 0; p_ < 16; ++p_) {                                     \
            const bool g_ = s_[2 * p_ + 1] > s_[2 * p_];                      \
            v16_[p_] = g_ ? s_[2 * p_ + 1] : s_[2 * p_];                      \
            x16_[p_] = g_ ? 2 * p_ + 1 : 2 * p_;                              \
        }                                                                     \
        float v8_[8]; int x8_[8];                                             \
        _Pragma("unroll")                                                     \
        for (int p_ = 0; p_ < 8; ++p_) {                                      \
            const bool g_ = v16_[2 * p_ + 1] > v16_[2 * p_];                  \
            v8_[p_] = g_ ? v16_[2 * p_ + 1] : v16_[2 * p_];                   \
            x8_[p_] = g_ ? x16_[2 * p_ + 1] : x16_[2 * p_];                   \
        }                                                                     \
        float v4_[4]; int x4_[4];                                             \
        _Pragma("unroll")                                                     \
        for (int p_ = 0; p_ < 4; ++p_) {                                      \
            const bool g_ = v8_[2 * p_ + 1] > v8_[2 * p_];                    \
            v4_[p_] = g_ ? v8_[2 * p_ + 1] : v8_[2 * p_];                     \
            x4_[p_] = g_ ? x8_[2 * p_ + 1] : x8_[2 * p_];                     \
        }                                                                     \
        float v2_[2]; int x2_[2];                                             \
        _Pragma("unroll")                                                     \
        for (int p_ = 0; p_ < 2; ++p_) {                                      \
            const bool g_ = v4_[2 * p_ + 1] > v4_[2 * p_];                    \
            v2_[p_] = g_ ? v4_[2 * p_ + 1] : v4_[2 * p_];                     \
            x2_[p_] = g_ ? x4_[2 * p_ + 1] : x4_[2 * p_];                     \
        }                                                                     \
        const bool gf_ = v2_[1] > v2_[0];                                     \
        float v_ = gf_ ? v2_[1] : v2_[0];                                     \
        int   x_ = ib + (gf_ ? x2_[1] : x2_[0]);                              \
        {                                                                     \
            const float pv_ = __int_as_float(__builtin_amdgcn_update_dpp(     \
                0, __float_as_int(v_), 0xB1, 0xF, 0xF, true));                \
            const int   px_ = __builtin_amdgcn_update_dpp(                    \
                0, x_, 0xB1, 0xF, 0xF, true);                                 \
            const bool  pl_ = d & 1;                                          \
            const bool  tk_ = (pv_ > v_) || (pl_ && (pv_ == v_));             \
            if (tk_) { v_ = pv_; x_ = px_; }                                  \
        }                                                                     \
        {                                                                     \
            const float pv_ = __int_as_float(__builtin_amdgcn_update_dpp(     \
                0, __float_as_int(v_), 0x4E, 0xF, 0xF, true));                \
            const int   px_ = __builtin_amdgcn_update_dpp(                    \
                0, x_, 0x4E, 0xF, 0xF, true);                                 \
            const bool  pl_ = (d >> 1) & 1;                                   \
            const bool  tk_ = (pv_ > v_) || (pl_ && (pv_ == v_));             \
            if (tk_) { v_ = pv_; x_ = px_; }                                  \
        }                                                                     \
        if (d == 0) {                                                         \
            alphabuf[((T_) + 1) & 1][fj] = v_ + (PQ_);                        \
            pack |= (unsigned)x_ << (8 * (C_));                               \
            if ((C_) == 3) {                                                  \
                bp4[((size_t)(((T_) - 1) >> 2) * B_DIM + b) * C_DIM + j] =    \
                    pack;                                                     \
                pack = 0;                                                     \
            }                                                                 \
            if ((T_) + 4 < T_LEN) PQ_ = potb[((T_) + 4) * C_DIM + j];         \
        }                                                                     \
        LDS_BARRIER();                                                        \
    }

    for (int t = 1; t < 2045; t += 4) {
        STEP(t + 0, 0, pq0)
        STEP(t + 1, 1, pq1)
        STEP(t + 2, 2, pq2)
        STEP(t + 3, 3, pq3)
    }
    STEP(2045, 0, pq0)
    STEP(2046, 1, pq1)
    STEP(2047, 2, pq2)
    if (d == 0)
        bp4[((size_t)511 * B_DIM + b) * C_DIM + j] = pack;
#undef STEP
#undef ADD_TR

    if (tid < 64) {
        const float* af = alphabuf[0];
        const float v0 = af[FSKEW(tid)];
        const float v1 = af[FSKEW(tid + 64)];
        float v = v0; int x = tid;
        if (v1 > v0) { v = v1; x = tid + 64; }
#pragma unroll
        for (int mk = 1; mk < 64; mk <<= 1) {
            const float pv = __shfl_xor(v, mk);
            const int   px = __shfl_xor(x, mk);
            if (pv > v || (pv == v && px < x)) { v = pv; x = px; }
        }
        if (tid == 0) lastTag[b] = x;
    }
}

__global__ __launch_bounds__(64, 1) void viterbi_bwd(
    const unsigned* __restrict__ bp4,
    const int* __restrict__ lastTag,
    float* __restrict__ out)
{
    const int b = blockIdx.x;
    const int l = threadIdx.x;
    float* outb = out + (size_t)b * T_LEN;

    unsigned qa0 = 0, qb0 = 0, qa1 = 0, qb1 = 0,
             qa2 = 0, qb2 = 0, qa3 = 0, qb3 = 0;

    auto ld = [&](int s4, unsigned& A, unsigned& B) {
        if (s4 >= 0) {
            const unsigned* r = bp4 + ((size_t)s4 * B_DIM + b) * C_DIM;
            A = r[l];
            B = r[l + 64];
        }
    };
    ld(511, qa0, qb0);
    ld(510, qa1, qb1);
    ld(509, qa2, qb2);
    ld(508, qa3, qb3);

    int cur = lastTag[b];

    auto ext = [&](unsigned rA, unsigned rB, int c, int byte) -> int {
        const int addr = (c & 63) << 2;
        const int vA = __builtin_amdgcn_ds_bpermute(addr, (int)rA);
        const int vB = __builtin_amdgcn_ds_bpermute(addr, (int)rB);
        const int v = (c & 64) ? vB : vA;
        return (v >> (byte * 8)) & 0xFF;
    };

    {
        const unsigned rA = qa0, rB = qb0;
        const float t3 = (float)cur;
        cur = ext(rA, rB, cur, 2); const float t2 = (float)cur;
        cur = ext(rA, rB, cur, 1); const float t1 = (float)cur;
        cur = ext(rA, rB, cur, 0); const float t0 = (float)cur;
        if (l == 0) *(float4*)(outb + 4 * 511) = make_float4(t0, t1, t2, t3);
        qa0 = qa1; qb0 = qb1; qa1 = qa2; qb1 = qb2; qa2 = qa3; qb2 = qb3;
        ld(507, qa3, qb3);
    }

    for (int s4 = 510; s4 >= 0; --s4) {
        const unsigned rA = qa0, rB = qb0;
        cur = ext(rA, rB, cur, 3); const float t3 = (float)cur;
        cur = ext(rA, rB, cur, 2); const float t2 = (float)cur;
        cur = ext(rA, rB, cur, 1); const float t1 = (float)cur;
        cur = ext(rA, rB, cur, 0); const float t0 = (float)cur;
        if (l == 0) *(float4*)(outb + 4 * s4) = make_float4(t0, t1, t2, t3);
        qa0 = qa1; qb0 = qb1; qa1 = qa2; qb1 = qb2; qa2 = qa3; qb2 = qb3;
        ld(s4 - 4, qa3, qb3);
    }
}

extern "C" void kernel_launch(void* const* d_in, const int* in_sizes, int n_in,
                              void* d_out, int out_size, void* d_ws, size_t ws_size,
                              hipStream_t stream)
{
    const float* pot   = (const float*)d_in[0];   // [128, 2048, 128] f32
    const float* trans = (const float*)d_in[1];   // [128, 128] f32
    float* out = (float*)d_out;                   // [128, 2048] f32 (tags)

    const size_t alphaBytes = (size_t)B_DIM * NSTEP * C_DIM * sizeof(float); // 134,152,192
    if (ws_size >= alphaBytes + 512) {
        // NEW PATH: alpha-store forward + recompute-argmax backtrack
        float* alphaG = (float*)d_ws;
        int* lastTag  = (int*)((char*)d_ws + alphaBytes);
        viterbi_fwd_a<<<B_DIM, 512, 0, stream>>>(pot, trans, alphaG, lastTag);
        viterbi_bwd_a<<<B_DIM, 64, 0, stream>>>(alphaG, trans, lastTag, out);
    } else {
        // FALLBACK: bp4 path (32 MiB workspace), previous best
        unsigned* bp4 = (unsigned*)d_ws;
        int* lastTag  = (int*)((char*)d_ws + (size_t)NS4 * B_DIM * C_DIM * 4);
        viterbi_fwd<<<B_DIM, 512, 0, stream>>>(pot, trans, bp4, lastTag);
        viterbi_bwd<<<B_DIM, 64, 0, stream>>>(bp4, lastTag, out);
    }
}